// Round 3
// baseline (140.921 us; speedup 1.0000x reference)
//
#include <hip/hip_runtime.h>
#include <hip/hip_bf16.h>

#ifndef __has_builtin
#define __has_builtin(x) 0
#endif

__device__ __forceinline__ float fast_exp2(float x) {
#if __has_builtin(__builtin_amdgcn_exp2f)
  return __builtin_amdgcn_exp2f(x);
#else
  return exp2f(x);
#endif
}
__device__ __forceinline__ float fast_rcp(float x) {
#if __has_builtin(__builtin_amdgcn_rcpf)
  return __builtin_amdgcn_rcpf(x);
#else
  return 1.0f / x;
#endif
}

constexpr int Bsz = 8, QL = 128, KL = 512, DD = 256, UU = 256;
constexpr int PR = 4;                    // rows per proj block (1280 blocks)
constexpr int DT = 8;                    // d-chunk in proj pipeline
constexpr float NEG_INF = -1e6f;
constexpr float C2 = 2.885390081777927f; // 2*log2(e): exp2(C2*x) == exp(2x)
constexpr int NITEMS = Bsz * QL;         // 1024 fused work items (b, q)

// Work-queue counter lives in module memory, NOT the workspace (round-2's
// ctr-at-ws+5MB was a probable OOB write -> container crash). Reset by
// proj block 0 each launch; stream order + kernel-boundary flush make it
// visible to all XCDs before any fused block pops.
__device__ int g_ctr = 0;

// ---------------------------------------------------------------------------
// Kernel 1: projections, pre-scaled by C2.
//   qp  [b][q][u]  natural   (fused reads q-rows as wave-uniform s_loads)
//   kpT [b][u][k]  transposed (fused walks u for fixed k -> contiguous k per
//                   wave; free here: thread owns a 4-k x 1-u column = float4)
// ---------------------------------------------------------------------------
__global__ __launch_bounds__(256) void proj_kernel(
    const float* __restrict__ query, const float* __restrict__ key,
    const float* __restrict__ Wq, const float* __restrict__ Wk,
    const int* __restrict__ valid_len,
    float* __restrict__ qp, float* __restrict__ kpT)
{
  const int u   = threadIdx.x;
  const int blk = blockIdx.x;
  if (blk == 0 && u == 0) atomicExch(&g_ctr, 0);   // device-scope reset

  constexpr int QBLKS = Bsz * QL / PR;   // 256
  const bool isQ = blk < QBLKS;
  const int  m0  = isQ ? blk * PR : (blk - QBLKS) * PR;

  const int kb_b = m0 / KL, kb_k0 = m0 % KL;   // only meaningful for K rows
  if (!isQ) {
    if (kb_k0 >= valid_len[kb_b]) return;      // masked rows never read
  }
  const float* __restrict__ in = isQ ? query : key;
  const float* __restrict__ W  = isQ ? Wq : Wk;
  const float* r0 = in + (size_t)m0 * DD;

  float acc[PR];
#pragma unroll
  for (int r = 0; r < PR; ++r) acc[r] = 0.f;

  float  w_c[DT], w_n[DT];
  float4 r_c[PR][2], r_n[PR][2];

#pragma unroll
  for (int j = 0; j < DT; ++j) w_c[j] = W[j * UU + u];
#pragma unroll
  for (int r = 0; r < PR; ++r) {
    r_c[r][0] = *reinterpret_cast<const float4*>(r0 + r * DD);
    r_c[r][1] = *reinterpret_cast<const float4*>(r0 + r * DD + 4);
  }

  for (int d = 0; d < DD; d += DT) {
    const int dn = (d + DT < DD) ? d + DT : 0;   // clamped dummy on last
#pragma unroll
    for (int j = 0; j < DT; ++j) w_n[j] = W[(dn + j) * UU + u];
#pragma unroll
    for (int r = 0; r < PR; ++r) {
      r_n[r][0] = *reinterpret_cast<const float4*>(r0 + r * DD + dn);
      r_n[r][1] = *reinterpret_cast<const float4*>(r0 + r * DD + dn + 4);
    }
#pragma unroll
    for (int r = 0; r < PR; ++r) {
      float a = acc[r];
      a = fmaf(r_c[r][0].x, w_c[0], a);
      a = fmaf(r_c[r][0].y, w_c[1], a);
      a = fmaf(r_c[r][0].z, w_c[2], a);
      a = fmaf(r_c[r][0].w, w_c[3], a);
      a = fmaf(r_c[r][1].x, w_c[4], a);
      a = fmaf(r_c[r][1].y, w_c[5], a);
      a = fmaf(r_c[r][1].z, w_c[6], a);
      a = fmaf(r_c[r][1].w, w_c[7], a);
      acc[r] = a;
    }
#pragma unroll
    for (int j = 0; j < DT; ++j) w_c[j] = w_n[j];
#pragma unroll
    for (int r = 0; r < PR; ++r) { r_c[r][0] = r_n[r][0]; r_c[r][1] = r_n[r][1]; }
  }

  if (isQ) {
    float* o = qp + (size_t)m0 * UU + u;       // natural [row][u], coalesced
#pragma unroll
    for (int r = 0; r < PR; ++r) o[(size_t)r * UU] = acc[r] * C2;
  } else {
    float4 cv;
    cv.x = acc[0] * C2; cv.y = acc[1] * C2;
    cv.z = acc[2] * C2; cv.w = acc[3] * C2;
    *reinterpret_cast<float4*>(kpT + ((size_t)kb_b * UU + u) * KL + kb_k0) = cv;
  }
}

// ---------------------------------------------------------------------------
// Kernel 2: persistent blocks + LPT dynamic work queue.
// 768 blocks (3/CU, co-resident). Items = 1024 (b,q) pairs popped from
// g_ctr. Item order is longest-processing-time-first: rank = item>>7 indexes
// batches sorted by vlen descending (work ~ vlen). Fat items start first on
// whatever CU is free; the tail is the thinnest items -> makespan balanced
// regardless of dispatch topology (fixes r0/r1's b=blk&7 batch->XCD pinning).
// s_item is double-buffered by iteration parity: t0's write for iter i+1
// goes to the slot NOT being read in iter i, and a barrier separates the
// write from its readers (fixes round-2's race).
// ---------------------------------------------------------------------------
__global__ __launch_bounds__(256) void fused_attn_kernel(
    const float* __restrict__ value, const int* __restrict__ valid_len,
    const float* __restrict__ v_w, const float* __restrict__ qp,
    const float* __restrict__ kpT, float* __restrict__ out)
{
  __shared__ __align__(16) float sps[KL];      // 2 KB: exp weights
  __shared__ float redM[4], redS[4];
  __shared__ int   s_item[2];

  const int t = threadIdx.x;
  const int w = t >> 6, l = t & 63;
  const int kb = 128 * w + 2 * l;              // lane's first k in its strip

  // vlen table (block-uniform, identical across all blocks)
  int vl[8];
#pragma unroll
  for (int i = 0; i < 8; ++i) vl[i] = valid_len[i];

  for (int it = 0; ; ++it) {
    if (t == 0) s_item[it & 1] = atomicAdd(&g_ctr, 1);
    __syncthreads();                           // also fences sps/red reuse
    const int item = s_item[it & 1];
    if (item >= NITEMS) break;

    // LPT mapping: rank r = vlen-descending batch rank (ties by index)
    const int r  = item >> 7;                  // 0..7, 0 = fattest batch
    const int q0 = item & 127;
    int b = 0;
#pragma unroll
    for (int i = 0; i < 8; ++i) {
      int rk = 0;
#pragma unroll
      for (int j = 0; j < 8; ++j)
        rk += (vl[j] > vl[i]) || (vl[j] == vl[i] && j < i);
      if (rk == r) b = i;
    }
    const int vlen = vl[b];

    const float* __restrict__ qrow = qp + (size_t)(b * QL + q0) * UU;

    // ---- scores for this wave's k-strip ----
    float a0 = 0.f, a1 = 0.f;
    if (128 * w < vlen) {
      const float* __restrict__ kcol = kpT + (size_t)b * UU * KL + kb;
      float2 c[8], n[8];
#pragma unroll
      for (int j = 0; j < 8; ++j)
        c[j] = *reinterpret_cast<const float2*>(kcol + (size_t)j * KL);

      for (int u0 = 0; u0 < UU; u0 += 8) {
        const int un = (u0 + 8 < UU) ? u0 + 8 : 0;   // clamped dummy on last
#pragma unroll
        for (int j = 0; j < 8; ++j)
          n[j] = *reinterpret_cast<const float2*>(kcol + (size_t)(un + j) * KL);
#pragma unroll
        for (int j = 0; j < 8; ++j) {
          const float qv = qrow[u0 + j];   // block-uniform -> s_load
          const float wv = v_w[u0 + j];    // block-uniform -> s_load
          const float e0 = fast_exp2(qv + c[j].x);
          const float e1 = fast_exp2(qv + c[j].y);
          a0 = fmaf(wv, fast_rcp(1.0f + e0), a0);
          a1 = fmaf(wv, fast_rcp(1.0f + e1), a1);
        }
#pragma unroll
        for (int j = 0; j < 8; ++j) c[j] = n[j];
      }
    }
    // score = -2*sum(v_w*sigmoid) (constant sum(v_w) dropped by softmax
    // shift-invariance); masked k -> NEG_INF
    const float s0 = (kb     < vlen) ? -(a0 + a0) : NEG_INF;
    const float s1 = (kb + 1 < vlen) ? -(a1 + a1) : NEG_INF;

    // ---- softmax, in-register; each wave reduces its own strip ----
    float mx = fmaxf(s0, s1);
#pragma unroll
    for (int off = 32; off >= 1; off >>= 1)
      mx = fmaxf(mx, __shfl_xor(mx, off, 64));
    if (l == 0) redM[w] = mx;
    __syncthreads();
    const float m = fmaxf(fmaxf(redM[0], redM[1]), fmaxf(redM[2], redM[3]));

    const float e0 = __expf(s0 - m);
    const float e1 = __expf(s1 - m);
    *reinterpret_cast<float2*>(&sps[kb]) = make_float2(e0, e1);
    float ss = e0 + e1;
#pragma unroll
    for (int off = 32; off >= 1; off >>= 1)
      ss += __shfl_xor(ss, off, 64);
    if (l == 0) redS[w] = ss;
    __syncthreads();
    const float inv = fast_rcp(redS[0] + redS[1] + redS[2] + redS[3]);

    // ---- PV: thread = d; unnormalized weights, scale at the end ----
    const float* __restrict__ vb = value + (size_t)b * KL * DD + t;
    float o0 = 0.f;
    const int kmax = (vlen + 15) & ~15;        // sps beyond vlen is exactly 0

    float vc[16], vn[16];
#pragma unroll
    for (int j = 0; j < 16; ++j) vc[j] = vb[(size_t)j * DD];
    for (int k = 0; k < kmax; k += 16) {
      const int kn = (k + 16 < kmax) ? k + 16 : 0;
#pragma unroll
      for (int j = 0; j < 16; ++j) vn[j] = vb[(size_t)(kn + j) * DD];
#pragma unroll
      for (int j = 0; j < 16; ++j) o0 = fmaf(sps[k + j], vc[j], o0);
#pragma unroll
      for (int j = 0; j < 16; ++j) vc[j] = vn[j];
    }
    out[(size_t)(b * QL + q0) * DD + t] = o0 * inv;
  }
}

extern "C" void kernel_launch(void* const* d_in, const int* in_sizes, int n_in,
                              void* d_out, int out_size, void* d_ws, size_t ws_size,
                              hipStream_t stream) {
  const float* query     = (const float*)d_in[0];
  const float* key       = (const float*)d_in[1];
  const float* value     = (const float*)d_in[2];
  const int*   valid_len = (const int*)d_in[3];
  const float* Wq        = (const float*)d_in[4];
  const float* Wk        = (const float*)d_in[5];
  const float* v_w       = (const float*)d_in[6];
  float* out = (float*)d_out;

  float* qp  = (float*)d_ws;                        // B*QL*U floats (1 MB)
  float* kpT = qp + (size_t)Bsz * QL * UU;          // B*U*KL floats (4 MB)

  const int proj_blocks = (Bsz * QL + Bsz * KL) / PR;   // 1280
  proj_kernel<<<proj_blocks, 256, 0, stream>>>(query, key, Wq, Wk, valid_len,
                                               qp, kpT);

  const int fused_blocks = 768;                     // 3/CU, persistent + queue
  fused_attn_kernel<<<fused_blocks, 256, 0, stream>>>(value, valid_len, v_w,
                                                      qp, kpT, out);
}

// Round 4
// 132.593 us; speedup vs baseline: 1.0628x; 1.0628x over previous
//
#include <hip/hip_runtime.h>
#include <hip/hip_bf16.h>

#ifndef __has_builtin
#define __has_builtin(x) 0
#endif

__device__ __forceinline__ float fast_exp2(float x) {
#if __has_builtin(__builtin_amdgcn_exp2f)
  return __builtin_amdgcn_exp2f(x);
#else
  return exp2f(x);
#endif
}
__device__ __forceinline__ float fast_rcp(float x) {
#if __has_builtin(__builtin_amdgcn_rcpf)
  return __builtin_amdgcn_rcpf(x);
#else
  return 1.0f / x;
#endif
}

constexpr int Bsz = 8, QL = 128, KL = 512, DD = 256, UU = 256;
constexpr int PR = 4;                    // rows per proj block (1280 blocks)
constexpr int DT = 8;                    // d-chunk in proj pipeline
constexpr float NEG_INF = -1e6f;
constexpr float C2 = 2.885390081777927f; // 2*log2(e): exp2(C2*x) == exp(2x)

// ---------------------------------------------------------------------------
// Kernel 1: projections, pre-scaled by C2.  (unchanged from round 1/3; no
// queue counter anymore — fused is static.)
//   qp  [b][q][u]  natural   (fused reads q-rows as wave-uniform s_loads)
//   kpT [b][u][k]  transposed (fused walks u for fixed k -> contiguous k per
//                   wave; free here: thread owns a 4-k x 1-u column = float4)
// ---------------------------------------------------------------------------
__global__ __launch_bounds__(256) void proj_kernel(
    const float* __restrict__ query, const float* __restrict__ key,
    const float* __restrict__ Wq, const float* __restrict__ Wk,
    const int* __restrict__ valid_len,
    float* __restrict__ qp, float* __restrict__ kpT)
{
  const int u   = threadIdx.x;
  const int blk = blockIdx.x;

  constexpr int QBLKS = Bsz * QL / PR;   // 256
  const bool isQ = blk < QBLKS;
  const int  m0  = isQ ? blk * PR : (blk - QBLKS) * PR;

  const int kb_b = m0 / KL, kb_k0 = m0 % KL;   // only meaningful for K rows
  if (!isQ) {
    if (kb_k0 >= valid_len[kb_b]) return;      // masked rows never read
  }
  const float* __restrict__ in = isQ ? query : key;
  const float* __restrict__ W  = isQ ? Wq : Wk;
  const float* r0 = in + (size_t)m0 * DD;

  float acc[PR];
#pragma unroll
  for (int r = 0; r < PR; ++r) acc[r] = 0.f;

  float  w_c[DT], w_n[DT];
  float4 r_c[PR][2], r_n[PR][2];

#pragma unroll
  for (int j = 0; j < DT; ++j) w_c[j] = W[j * UU + u];
#pragma unroll
  for (int r = 0; r < PR; ++r) {
    r_c[r][0] = *reinterpret_cast<const float4*>(r0 + r * DD);
    r_c[r][1] = *reinterpret_cast<const float4*>(r0 + r * DD + 4);
  }

  for (int d = 0; d < DD; d += DT) {
    const int dn = (d + DT < DD) ? d + DT : 0;   // clamped dummy on last
#pragma unroll
    for (int j = 0; j < DT; ++j) w_n[j] = W[(dn + j) * UU + u];
#pragma unroll
    for (int r = 0; r < PR; ++r) {
      r_n[r][0] = *reinterpret_cast<const float4*>(r0 + r * DD + dn);
      r_n[r][1] = *reinterpret_cast<const float4*>(r0 + r * DD + dn + 4);
    }
#pragma unroll
    for (int r = 0; r < PR; ++r) {
      float a = acc[r];
      a = fmaf(r_c[r][0].x, w_c[0], a);
      a = fmaf(r_c[r][0].y, w_c[1], a);
      a = fmaf(r_c[r][0].z, w_c[2], a);
      a = fmaf(r_c[r][0].w, w_c[3], a);
      a = fmaf(r_c[r][1].x, w_c[4], a);
      a = fmaf(r_c[r][1].y, w_c[5], a);
      a = fmaf(r_c[r][1].z, w_c[6], a);
      a = fmaf(r_c[r][1].w, w_c[7], a);
      acc[r] = a;
    }
#pragma unroll
    for (int j = 0; j < DT; ++j) w_c[j] = w_n[j];
#pragma unroll
    for (int r = 0; r < PR; ++r) { r_c[r][0] = r_n[r][0]; r_c[r][1] = r_n[r][1]; }
  }

  if (isQ) {
    float* o = qp + (size_t)m0 * UU + u;       // natural [row][u], coalesced
#pragma unroll
    for (int r = 0; r < PR; ++r) o[(size_t)r * UU] = acc[r] * C2;
  } else {
    float4 cv;
    cv.x = acc[0] * C2; cv.y = acc[1] * C2;
    cv.z = acc[2] * C2; cv.w = acc[3] * C2;
    *reinterpret_cast<float4*>(kpT + ((size_t)kb_b * UU + u) * KL + kb_k0) = cv;
  }
}

// ---------------------------------------------------------------------------
// Kernel 2: static 1:1, 512 blocks (2/CU), FQB=2 q-rows per block.
// Three structural fixes over r1/r3 (both measured ~60 us, VALUBusy ~30%):
//  - FQB=2: one kpT float2 load feeds 4 sigmoids; value loads feed 2 outputs
//    -> kpT+value L2 traffic halved, VMEM issue per sigmoid halved.
//  - strip rotation s=(w+qq)&3: wave w handles k-strip s. Without rotation,
//    strip w lands on SIMD w%4 and strips beyond vlen idle -> SIMD0 100%
//    loaded, SIMD3 25% (avg util <=62.5%, SIMD0 = makespan). Rotation
//    decorrelates strip-idleness from SIMD index.
//  - 2-XCD batch split: block g (XCD g&7) <-> item via permutation putting
//    batch b on XCDs {b,(b+4)&7} only -> fat-batch work spread 2x while the
//    per-XCD working set (kpT+value of 2 half-batches ~2MB) stays L2-local
//    (r3's global queue replicated every batch on all 8 L2s: FETCH x5.5).
// No queue, no atomics, no device globals.
// ---------------------------------------------------------------------------
__global__ __launch_bounds__(256) void fused_attn_kernel(
    const float* __restrict__ value, const int* __restrict__ valid_len,
    const float* __restrict__ v_w, const float* __restrict__ qp,
    const float* __restrict__ kpT, float* __restrict__ out)
{
  __shared__ __align__(16) float2 sps[KL];     // 4 KB: exp weights (row0,row1)
  __shared__ float2 redM[4], redS[4];

  const int t = threadIdx.x;
  const int w = t >> 6, l = t & 63;

  // block <-> (b, qq) permutation; XCD(g) = g&7 (heuristic, perf-only)
  const int g  = blockIdx.x;                   // 0..511
  const int k4 = g >> 3, x = g & 7;
  const int b  = (k4 & 1) ? ((x + 4) & 7) : x;
  const int qq = (k4 >> 1) + ((k4 & 1) << 5);  // 0..63
  const int q0 = qq * 2;

  const int vlen = valid_len[b];
  const int s  = (w + qq) & 3;                 // rotated k-strip for this wave
  const int kb = 128 * s + 2 * l;              // lane's first k

  const float* __restrict__ qrow0 = qp + (size_t)(b * QL + q0) * UU;
  const float* __restrict__ qrow1 = qrow0 + UU;

  // ---- scores: 2 k x 2 q per lane ----
  float a00 = 0.f, a01 = 0.f, a10 = 0.f, a11 = 0.f;  // [row][kslot]
  if (128 * s < vlen) {
    const float* __restrict__ kcol = kpT + (size_t)b * UU * KL + kb;
    float2 c[8], n[8];
#pragma unroll
    for (int j = 0; j < 8; ++j)
      c[j] = *reinterpret_cast<const float2*>(kcol + (size_t)j * KL);

    for (int u0 = 0; u0 < UU; u0 += 8) {
      const int un = (u0 + 8 < UU) ? u0 + 8 : 0;   // clamped dummy on last
#pragma unroll
      for (int j = 0; j < 8; ++j)
        n[j] = *reinterpret_cast<const float2*>(kcol + (size_t)(un + j) * KL);
#pragma unroll
      for (int j = 0; j < 8; ++j) {
        const float q0v = qrow0[u0 + j];  // block-uniform -> s_load
        const float q1v = qrow1[u0 + j];  // block-uniform -> s_load
        const float wv  = v_w[u0 + j];    // block-uniform -> s_load
        const float e00 = fast_exp2(q0v + c[j].x);
        const float e01 = fast_exp2(q0v + c[j].y);
        const float e10 = fast_exp2(q1v + c[j].x);
        const float e11 = fast_exp2(q1v + c[j].y);
        a00 = fmaf(wv, fast_rcp(1.0f + e00), a00);
        a01 = fmaf(wv, fast_rcp(1.0f + e01), a01);
        a10 = fmaf(wv, fast_rcp(1.0f + e10), a10);
        a11 = fmaf(wv, fast_rcp(1.0f + e11), a11);
      }
#pragma unroll
      for (int j = 0; j < 8; ++j) c[j] = n[j];
    }
  }
  // score = -2*sum(v_w*sigmoid) (constant sum(v_w) dropped by softmax
  // shift-invariance); masked k -> NEG_INF
  const float s00 = (kb     < vlen) ? -(a00 + a00) : NEG_INF;
  const float s01 = (kb + 1 < vlen) ? -(a01 + a01) : NEG_INF;
  const float s10 = (kb     < vlen) ? -(a10 + a10) : NEG_INF;
  const float s11 = (kb + 1 < vlen) ? -(a11 + a11) : NEG_INF;

  // ---- softmax (both rows at once), in-register per wave ----
  float mx0 = fmaxf(s00, s01);
  float mx1 = fmaxf(s10, s11);
#pragma unroll
  for (int off = 32; off >= 1; off >>= 1) {
    mx0 = fmaxf(mx0, __shfl_xor(mx0, off, 64));
    mx1 = fmaxf(mx1, __shfl_xor(mx1, off, 64));
  }
  if (l == 0) redM[w] = make_float2(mx0, mx1);
  __syncthreads();
  const float m0 = fmaxf(fmaxf(redM[0].x, redM[1].x), fmaxf(redM[2].x, redM[3].x));
  const float m1 = fmaxf(fmaxf(redM[0].y, redM[1].y), fmaxf(redM[2].y, redM[3].y));

  const float e00 = __expf(s00 - m0);
  const float e01 = __expf(s01 - m0);
  const float e10 = __expf(s10 - m1);
  const float e11 = __expf(s11 - m1);
  // sps[kb]=(row0,row1) @k=kb ; sps[kb+1] @k=kb+1 -> one float4 store
  {
    float4 sv; sv.x = e00; sv.y = e10; sv.z = e01; sv.w = e11;
    *reinterpret_cast<float4*>(&sps[kb]) = sv;
  }
  float ss0 = e00 + e01;
  float ss1 = e10 + e11;
#pragma unroll
  for (int off = 32; off >= 1; off >>= 1) {
    ss0 += __shfl_xor(ss0, off, 64);
    ss1 += __shfl_xor(ss1, off, 64);
  }
  if (l == 0) redS[w] = make_float2(ss0, ss1);
  __syncthreads();
  const float inv0 = fast_rcp(redS[0].x + redS[1].x + redS[2].x + redS[3].x);
  const float inv1 = fast_rcp(redS[0].y + redS[1].y + redS[2].y + redS[3].y);

  // ---- PV: thread = d; unnormalized weights, scale at the end ----
  const float* __restrict__ vb = value + (size_t)b * KL * DD + t;
  float o0 = 0.f, o1 = 0.f;
  const int kmax = (vlen + 15) & ~15;          // sps beyond vlen is exactly 0

  float vc[16], vn[16];
#pragma unroll
  for (int j = 0; j < 16; ++j) vc[j] = vb[(size_t)j * DD];
  for (int k = 0; k < kmax; k += 16) {
    const int kn = (k + 16 < kmax) ? k + 16 : 0;
#pragma unroll
    for (int j = 0; j < 16; ++j) vn[j] = vb[(size_t)(kn + j) * DD];
#pragma unroll
    for (int j = 0; j < 16; ++j) {
      const float2 p = sps[k + j];             // wave-uniform broadcast
      o0 = fmaf(p.x, vc[j], o0);
      o1 = fmaf(p.y, vc[j], o1);
    }
#pragma unroll
    for (int j = 0; j < 16; ++j) vc[j] = vn[j];
  }
  out[(size_t)(b * QL + q0) * DD + t]     = o0 * inv0;
  out[(size_t)(b * QL + q0 + 1) * DD + t] = o1 * inv1;
}

extern "C" void kernel_launch(void* const* d_in, const int* in_sizes, int n_in,
                              void* d_out, int out_size, void* d_ws, size_t ws_size,
                              hipStream_t stream) {
  const float* query     = (const float*)d_in[0];
  const float* key       = (const float*)d_in[1];
  const float* value     = (const float*)d_in[2];
  const int*   valid_len = (const int*)d_in[3];
  const float* Wq        = (const float*)d_in[4];
  const float* Wk        = (const float*)d_in[5];
  const float* v_w       = (const float*)d_in[6];
  float* out = (float*)d_out;

  float* qp  = (float*)d_ws;                        // B*QL*U floats (1 MB)
  float* kpT = qp + (size_t)Bsz * QL * UU;          // B*U*KL floats (4 MB)

  const int proj_blocks = (Bsz * QL + Bsz * KL) / PR;   // 1280
  proj_kernel<<<proj_blocks, 256, 0, stream>>>(query, key, Wq, Wk, valid_len,
                                               qp, kpT);

  const int fused_blocks = Bsz * QL / 2;            // 512: (b, q-pair) items
  fused_attn_kernel<<<fused_blocks, 256, 0, stream>>>(value, valid_len, v_w,
                                                      qp, kpT, out);
}

// Round 5
// 117.936 us; speedup vs baseline: 1.1949x; 1.1243x over previous
//
#include <hip/hip_runtime.h>
#include <hip/hip_bf16.h>

#ifndef __has_builtin
#define __has_builtin(x) 0
#endif

__device__ __forceinline__ float fast_exp2(float x) {
#if __has_builtin(__builtin_amdgcn_exp2f)
  return __builtin_amdgcn_exp2f(x);
#else
  return exp2f(x);
#endif
}
__device__ __forceinline__ float fast_rcp(float x) {
#if __has_builtin(__builtin_amdgcn_rcpf)
  return __builtin_amdgcn_rcpf(x);
#else
  return 1.0f / x;
#endif
}

constexpr int Bsz = 8, QL = 128, KL = 512, DD = 256, UU = 256;
constexpr int PR = 4;                    // rows per proj block (1280 blocks)
constexpr int DT = 8;                    // d-chunk in proj pipeline
constexpr float NEG_INF = -1e6f;
constexpr float C2 = 2.885390081777927f; // 2*log2(e): exp2(C2*x) == exp(2x)

// ---------------------------------------------------------------------------
// Kernel 1: projections. NOW STORES EXPONENTIALS (exp-factorization):
//   qp  [b][q][u] = Eq = exp2(C2 * q~)   (fused reads as wave-uniform s_loads)
//   kpT [b][u][k] = Ek = exp2(C2 * k~)   (transposed; coalesced k per wave)
// Downstream: exp2(q~ + k~) == Eq * Ek, so the fused inner loop needs NO
// exp2 — just fma + rcp. Range: |C2*proj| <~ 10 -> Eq,Ek in [2^-10, 2^10],
// products fit fp32 easily. Masked-k rows stay unwritten (garbage): their
// lane-private accs may become inf/NaN but the score is overwritten by
// NEG_INF, so nothing propagates.
// ---------------------------------------------------------------------------
__global__ __launch_bounds__(256) void proj_kernel(
    const float* __restrict__ query, const float* __restrict__ key,
    const float* __restrict__ Wq, const float* __restrict__ Wk,
    const int* __restrict__ valid_len,
    float* __restrict__ qp, float* __restrict__ kpT)
{
  const int u   = threadIdx.x;
  const int blk = blockIdx.x;

  constexpr int QBLKS = Bsz * QL / PR;   // 256
  const bool isQ = blk < QBLKS;
  const int  m0  = isQ ? blk * PR : (blk - QBLKS) * PR;

  const int kb_b = m0 / KL, kb_k0 = m0 % KL;   // only meaningful for K rows
  if (!isQ) {
    if (kb_k0 >= valid_len[kb_b]) return;      // masked rows never read
  }
  const float* __restrict__ in = isQ ? query : key;
  const float* __restrict__ W  = isQ ? Wq : Wk;
  const float* r0 = in + (size_t)m0 * DD;

  float acc[PR];
#pragma unroll
  for (int r = 0; r < PR; ++r) acc[r] = 0.f;

  float  w_c[DT], w_n[DT];
  float4 r_c[PR][2], r_n[PR][2];

#pragma unroll
  for (int j = 0; j < DT; ++j) w_c[j] = W[j * UU + u];
#pragma unroll
  for (int r = 0; r < PR; ++r) {
    r_c[r][0] = *reinterpret_cast<const float4*>(r0 + r * DD);
    r_c[r][1] = *reinterpret_cast<const float4*>(r0 + r * DD + 4);
  }

  for (int d = 0; d < DD; d += DT) {
    const int dn = (d + DT < DD) ? d + DT : 0;   // clamped dummy on last
#pragma unroll
    for (int j = 0; j < DT; ++j) w_n[j] = W[(dn + j) * UU + u];
#pragma unroll
    for (int r = 0; r < PR; ++r) {
      r_n[r][0] = *reinterpret_cast<const float4*>(r0 + r * DD + dn);
      r_n[r][1] = *reinterpret_cast<const float4*>(r0 + r * DD + dn + 4);
    }
#pragma unroll
    for (int r = 0; r < PR; ++r) {
      float a = acc[r];
      a = fmaf(r_c[r][0].x, w_c[0], a);
      a = fmaf(r_c[r][0].y, w_c[1], a);
      a = fmaf(r_c[r][0].z, w_c[2], a);
      a = fmaf(r_c[r][0].w, w_c[3], a);
      a = fmaf(r_c[r][1].x, w_c[4], a);
      a = fmaf(r_c[r][1].y, w_c[5], a);
      a = fmaf(r_c[r][1].z, w_c[6], a);
      a = fmaf(r_c[r][1].w, w_c[7], a);
      acc[r] = a;
    }
#pragma unroll
    for (int j = 0; j < DT; ++j) w_c[j] = w_n[j];
#pragma unroll
    for (int r = 0; r < PR; ++r) { r_c[r][0] = r_n[r][0]; r_c[r][1] = r_n[r][1]; }
  }

  if (isQ) {
    float* o = qp + (size_t)m0 * UU + u;       // natural [row][u], coalesced
#pragma unroll
    for (int r = 0; r < PR; ++r) o[(size_t)r * UU] = fast_exp2(acc[r] * C2);
  } else {
    float4 cv;
    cv.x = fast_exp2(acc[0] * C2); cv.y = fast_exp2(acc[1] * C2);
    cv.z = fast_exp2(acc[2] * C2); cv.w = fast_exp2(acc[3] * C2);
    *reinterpret_cast<float4*>(kpT + ((size_t)kb_b * UU + u) * KL + kb_k0) = cv;
  }
}

// ---------------------------------------------------------------------------
// Kernel 2: 512 blocks x 512 threads (8 waves) = 16 waves/CU (2x r4's TLP).
//  - exp-factorized sigmoid: d = fma(Eq, Ek, 1); a = fma(wv, rcp(d), a)
//    -> 2 VALU + 1 trans per sigmoid (was 3 VALU + 2 trans). Floor ~6 us.
//  - 8 waves x 64-key strips, 1 k/lane x 2 q-rows; rotation s=(w+qq)&7
//    decorrelates masked-strip idleness from SIMD index at 64-key grain.
//  - rank-paired XCD split: XCD x hosts vlen-rank x (qq 0..31) and rank 7-x
//    (qq 32..63) -> fattest batch shares XCDs with thinnest; every batch
//    split over 2 XCDs; bijective block<->(b,qq) map.
//  - softmax in-register (redM/redS[8]); PV: thread=(row,d), all 8 waves,
//    float4 LDS broadcasts of weights, 16-deep value prefetch, unnormalized
//    weights scaled by 1/sum at the end.
// ---------------------------------------------------------------------------
__global__ __launch_bounds__(512) void fused_attn_kernel(
    const float* __restrict__ value, const int* __restrict__ valid_len,
    const float* __restrict__ v_w, const float* __restrict__ qp,
    const float* __restrict__ kpT, float* __restrict__ out)
{
  __shared__ __align__(16) float sps0[KL];     // 2 KB: exp weights row 0
  __shared__ __align__(16) float sps1[KL];     // 2 KB: exp weights row 1
  __shared__ float2 redM[8], redS[8];

  const int t = threadIdx.x;
  const int w = t >> 6, l = t & 63;

  // ---- block -> (b, qq): rank-paired XCD mapping ----
  const int g = blockIdx.x;                    // 0..511
  const int x = g & 7;                         // XCD (heuristic, perf-only)
  const int i = g >> 3;                        // 0..63
  int vl[8];
#pragma unroll
  for (int bi = 0; bi < 8; ++bi) vl[bi] = valid_len[bi];
  const int rk = (i < 32) ? x : (7 - x);       // vlen-desc rank wanted here
  int b = 0;
#pragma unroll
  for (int bi = 0; bi < 8; ++bi) {
    int r = 0;
#pragma unroll
    for (int bj = 0; bj < 8; ++bj)
      r += (vl[bj] > vl[bi]) || (vl[bj] == vl[bi] && bj < bi);
    if (r == rk) b = bi;
  }
  const int vlen = vl[b];
  const int qq = i;                            // 0..63 q-pair index
  const int q0 = qq * 2;

  const int s  = (w + qq) & 7;                 // rotated 64-key strip
  const int kb = 64 * s + l;                   // this lane's key

  const float* __restrict__ qrow0 = qp + (size_t)(b * QL + q0) * UU;  // Eq row0
  const float* __restrict__ qrow1 = qrow0 + UU;                       // Eq row1

  // ---- scores: 1 k x 2 q per lane, no exp2 in the loop ----
  float a0 = 0.f, a1 = 0.f;
  if (64 * s < vlen) {
    const float* __restrict__ kcol = kpT + (size_t)b * UU * KL + kb;
    float c[8], n[8];
#pragma unroll
    for (int j = 0; j < 8; ++j) c[j] = kcol[(size_t)j * KL];

    for (int u0 = 0; u0 < UU; u0 += 8) {
      const int un = (u0 + 8 < UU) ? u0 + 8 : 0;   // clamped dummy on last
#pragma unroll
      for (int j = 0; j < 8; ++j) n[j] = kcol[(size_t)(un + j) * KL];
#pragma unroll
      for (int j = 0; j < 8; ++j) {
        const float Eq0 = qrow0[u0 + j];  // block-uniform -> s_load
        const float Eq1 = qrow1[u0 + j];  // block-uniform -> s_load
        const float wv  = v_w[u0 + j];    // block-uniform -> s_load
        const float d0 = fmaf(Eq0, c[j], 1.0f);   // 1 + e^{2(q+k)}
        const float d1 = fmaf(Eq1, c[j], 1.0f);
        a0 = fmaf(wv, fast_rcp(d0), a0);
        a1 = fmaf(wv, fast_rcp(d1), a1);
      }
#pragma unroll
      for (int j = 0; j < 8; ++j) c[j] = n[j];
    }
  }
  // score = -2*sum(v_w*sigmoid); constant sum(v_w) dropped (shift-invariant)
  const float s0 = (kb < vlen) ? -(a0 + a0) : NEG_INF;
  const float s1 = (kb < vlen) ? -(a1 + a1) : NEG_INF;

  // ---- softmax, in-register; each wave reduces its strip (both rows) ----
  float mx0 = s0, mx1 = s1;
#pragma unroll
  for (int off = 32; off >= 1; off >>= 1) {
    mx0 = fmaxf(mx0, __shfl_xor(mx0, off, 64));
    mx1 = fmaxf(mx1, __shfl_xor(mx1, off, 64));
  }
  if (l == 0) redM[w] = make_float2(mx0, mx1);
  __syncthreads();
  float m0 = redM[0].x, m1 = redM[0].y;
#pragma unroll
  for (int j = 1; j < 8; ++j) {
    m0 = fmaxf(m0, redM[j].x);
    m1 = fmaxf(m1, redM[j].y);
  }

  const float e0 = __expf(s0 - m0);            // masked -> exactly 0
  const float e1 = __expf(s1 - m1);
  sps0[kb] = e0;
  sps1[kb] = e1;
  float ss0 = e0, ss1 = e1;
#pragma unroll
  for (int off = 32; off >= 1; off >>= 1) {
    ss0 += __shfl_xor(ss0, off, 64);
    ss1 += __shfl_xor(ss1, off, 64);
  }
  if (l == 0) redS[w] = make_float2(ss0, ss1);
  __syncthreads();
  float sum0 = redS[0].x, sum1 = redS[0].y;
#pragma unroll
  for (int j = 1; j < 8; ++j) {
    sum0 += redS[j].x;
    sum1 += redS[j].y;
  }
  const float inv0 = fast_rcp(sum0);           // sums >= 1
  const float inv1 = fast_rcp(sum1);

  // ---- PV: thread = (row, d); all 8 waves work the full k-range ----
  const int   r2 = t >> 8;                     // output row (0/1)
  const int   d  = t & 255;                    // feature dim
  const float* __restrict__ sp = r2 ? sps1 : sps0;
  const float  inv = r2 ? inv1 : inv0;
  const float* __restrict__ vb = value + (size_t)b * KL * DD + d;
  const int kmax = (vlen + 15) & ~15;          // sps beyond vlen is exactly 0

  float o = 0.f;
  float vc[16], vn[16];
#pragma unroll
  for (int j = 0; j < 16; ++j) vc[j] = vb[(size_t)j * DD];
  for (int k = 0; k < kmax; k += 16) {
    const int kn = (k + 16 < kmax) ? k + 16 : 0;
#pragma unroll
    for (int j = 0; j < 16; ++j) vn[j] = vb[(size_t)(kn + j) * DD];
    const float4* __restrict__ sp4 =
        reinterpret_cast<const float4*>(sp + k); // wave-uniform broadcasts
    const float4 p0 = sp4[0], p1 = sp4[1], p2 = sp4[2], p3 = sp4[3];
    o = fmaf(p0.x, vc[0],  o); o = fmaf(p0.y, vc[1],  o);
    o = fmaf(p0.z, vc[2],  o); o = fmaf(p0.w, vc[3],  o);
    o = fmaf(p1.x, vc[4],  o); o = fmaf(p1.y, vc[5],  o);
    o = fmaf(p1.z, vc[6],  o); o = fmaf(p1.w, vc[7],  o);
    o = fmaf(p2.x, vc[8],  o); o = fmaf(p2.y, vc[9],  o);
    o = fmaf(p2.z, vc[10], o); o = fmaf(p2.w, vc[11], o);
    o = fmaf(p3.x, vc[12], o); o = fmaf(p3.y, vc[13], o);
    o = fmaf(p3.z, vc[14], o); o = fmaf(p3.w, vc[15], o);
#pragma unroll
    for (int j = 0; j < 16; ++j) vc[j] = vn[j];
  }
  out[(size_t)(b * QL + q0 + r2) * DD + d] = o * inv;
}

extern "C" void kernel_launch(void* const* d_in, const int* in_sizes, int n_in,
                              void* d_out, int out_size, void* d_ws, size_t ws_size,
                              hipStream_t stream) {
  const float* query     = (const float*)d_in[0];
  const float* key       = (const float*)d_in[1];
  const float* value     = (const float*)d_in[2];
  const int*   valid_len = (const int*)d_in[3];
  const float* Wq        = (const float*)d_in[4];
  const float* Wk        = (const float*)d_in[5];
  const float* v_w       = (const float*)d_in[6];
  float* out = (float*)d_out;

  float* qp  = (float*)d_ws;                        // B*QL*U floats (1 MB)
  float* kpT = qp + (size_t)Bsz * QL * UU;          // B*U*KL floats (4 MB)

  const int proj_blocks = (Bsz * QL + Bsz * KL) / PR;   // 1280
  proj_kernel<<<proj_blocks, 256, 0, stream>>>(query, key, Wq, Wk, valid_len,
                                               qp, kpT);

  const int fused_blocks = Bsz * QL / 2;            // 512: (b, q-pair) items
  fused_attn_kernel<<<fused_blocks, 512, 0, stream>>>(value, valid_len, v_w,
                                                      qp, kpT, out);
}

// Round 6
// 113.261 us; speedup vs baseline: 1.2442x; 1.0413x over previous
//
#include <hip/hip_runtime.h>
#include <hip/hip_bf16.h>

#ifndef __has_builtin
#define __has_builtin(x) 0
#endif

__device__ __forceinline__ float fast_exp2(float x) {
#if __has_builtin(__builtin_amdgcn_exp2f)
  return __builtin_amdgcn_exp2f(x);
#else
  return exp2f(x);
#endif
}
__device__ __forceinline__ float fast_rcp(float x) {
#if __has_builtin(__builtin_amdgcn_rcpf)
  return __builtin_amdgcn_rcpf(x);
#else
  return 1.0f / x;
#endif
}

constexpr int Bsz = 8, QL = 128, KL = 512, DD = 256, UU = 256;
constexpr int PR = 4;                    // rows per proj block (1280 blocks)
constexpr int DT = 8;                    // d-chunk in proj pipeline
constexpr float NEG_INF = -1e6f;
constexpr float C2 = 2.885390081777927f; // 2*log2(e): exp2(C2*x) == exp(2x)

// ---------------------------------------------------------------------------
// Kernel 1: projections, stores exponentials (exp-factorization), unchanged
// from round 5:
//   qp  [b][q][u] = Eq = exp2(C2 * q~)
//   kpT [b][u][k] = Ek = exp2(C2 * k~)   (transposed)
// exp2(q~+k~) == Eq*Ek -> fused inner loop is fma + rcp only. Masked-k rows
// stay unwritten (garbage is discarded downstream).
// ---------------------------------------------------------------------------
__global__ __launch_bounds__(256) void proj_kernel(
    const float* __restrict__ query, const float* __restrict__ key,
    const float* __restrict__ Wq, const float* __restrict__ Wk,
    const int* __restrict__ valid_len,
    float* __restrict__ qp, float* __restrict__ kpT)
{
  const int u   = threadIdx.x;
  const int blk = blockIdx.x;

  constexpr int QBLKS = Bsz * QL / PR;   // 256
  const bool isQ = blk < QBLKS;
  const int  m0  = isQ ? blk * PR : (blk - QBLKS) * PR;

  const int kb_b = m0 / KL, kb_k0 = m0 % KL;   // only meaningful for K rows
  if (!isQ) {
    if (kb_k0 >= valid_len[kb_b]) return;      // masked rows never read
  }
  const float* __restrict__ in = isQ ? query : key;
  const float* __restrict__ W  = isQ ? Wq : Wk;
  const float* r0 = in + (size_t)m0 * DD;

  float acc[PR];
#pragma unroll
  for (int r = 0; r < PR; ++r) acc[r] = 0.f;

  float  w_c[DT], w_n[DT];
  float4 r_c[PR][2], r_n[PR][2];

#pragma unroll
  for (int j = 0; j < DT; ++j) w_c[j] = W[j * UU + u];
#pragma unroll
  for (int r = 0; r < PR; ++r) {
    r_c[r][0] = *reinterpret_cast<const float4*>(r0 + r * DD);
    r_c[r][1] = *reinterpret_cast<const float4*>(r0 + r * DD + 4);
  }

  for (int d = 0; d < DD; d += DT) {
    const int dn = (d + DT < DD) ? d + DT : 0;   // clamped dummy on last
#pragma unroll
    for (int j = 0; j < DT; ++j) w_n[j] = W[(dn + j) * UU + u];
#pragma unroll
    for (int r = 0; r < PR; ++r) {
      r_n[r][0] = *reinterpret_cast<const float4*>(r0 + r * DD + dn);
      r_n[r][1] = *reinterpret_cast<const float4*>(r0 + r * DD + dn + 4);
    }
#pragma unroll
    for (int r = 0; r < PR; ++r) {
      float a = acc[r];
      a = fmaf(r_c[r][0].x, w_c[0], a);
      a = fmaf(r_c[r][0].y, w_c[1], a);
      a = fmaf(r_c[r][0].z, w_c[2], a);
      a = fmaf(r_c[r][0].w, w_c[3], a);
      a = fmaf(r_c[r][1].x, w_c[4], a);
      a = fmaf(r_c[r][1].y, w_c[5], a);
      a = fmaf(r_c[r][1].z, w_c[6], a);
      a = fmaf(r_c[r][1].w, w_c[7], a);
      acc[r] = a;
    }
#pragma unroll
    for (int j = 0; j < DT; ++j) w_c[j] = w_n[j];
#pragma unroll
    for (int r = 0; r < PR; ++r) { r_c[r][0] = r_n[r][0]; r_c[r][1] = r_n[r][1]; }
  }

  if (isQ) {
    float* o = qp + (size_t)m0 * UU + u;       // natural [row][u], coalesced
#pragma unroll
    for (int r = 0; r < PR; ++r) o[(size_t)r * UU] = fast_exp2(acc[r] * C2);
  } else {
    float4 cv;
    cv.x = fast_exp2(acc[0] * C2); cv.y = fast_exp2(acc[1] * C2);
    cv.z = fast_exp2(acc[2] * C2); cv.w = fast_exp2(acc[3] * C2);
    *reinterpret_cast<float4*>(kpT + ((size_t)kb_b * UU + u) * KL + kb_k0) = cv;
  }
}

// ---------------------------------------------------------------------------
// Kernel 2: 512 blocks x 512 threads. U-SPLIT score phase (vlen-proportional):
//  - wave w computes partial scores over u in [32w, 32w+32) for ALL keys,
//    chunked 64 keys at a time (lane = key-in-chunk, c < ceil(vlen/64)).
//    Per-wave work is identical and ∝ vlen -> no idle waves, no fixed
//    256-u cost (r5's score wall time was vlen-INDEPENDENT: every active
//    wave ran the full u loop; avg vlen is only 288/512).
//  - partials cross-wave-reduced via LDS sp_part[8][8][64] (float2,
//    lane-stride 8B = conflict-free ds ops).
//  - Eq rows + v_w staged once as LDS float4 (Eq0,Eq1,wv,-): one broadcast
//    ds_read_b128 per u in the hot loop.
//  - softmax in-register as before (thread t owns key t).
//  - PV: split-k: thread=(h,d) h=k-half, d=dim; each value element loaded
//    once per block (halves value traffic); halves combined via LDS.
//  - rank-paired XCD mapping kept from r5.
// ---------------------------------------------------------------------------
__global__ __launch_bounds__(512) void fused_attn_kernel(
    const float* __restrict__ value, const int* __restrict__ valid_len,
    const float* __restrict__ v_w, const float* __restrict__ qp,
    const float* __restrict__ kpT, float* __restrict__ out)
{
  __shared__ __align__(16) float4 qpack[UU];       // 4 KB (Eq0,Eq1,wv,-)
  __shared__ __align__(16) float2 sp_part[8][8][64]; // 32 KB [wsrc][c][lane]
  __shared__ __align__(16) float  sps0[KL];        // 2 KB exp weights row 0
  __shared__ __align__(16) float  sps1[KL];        // 2 KB exp weights row 1
  __shared__ __align__(16) float2 opart[DD];       // 2 KB PV half-partials
  __shared__ float2 redM[8], redS[8];

  const int t = threadIdx.x;
  const int w = t >> 6, l = t & 63;

  // ---- block -> (b, qq): rank-paired XCD mapping (r5, verified) ----
  const int g = blockIdx.x;                    // 0..511
  const int x = g & 7;                         // XCD (heuristic, perf-only)
  const int i = g >> 3;                        // 0..63
  int vl[8];
#pragma unroll
  for (int bi = 0; bi < 8; ++bi) vl[bi] = valid_len[bi];
  const int rk = (i < 32) ? x : (7 - x);       // vlen-desc rank wanted here
  int b = 0;
#pragma unroll
  for (int bi = 0; bi < 8; ++bi) {
    int r = 0;
#pragma unroll
    for (int bj = 0; bj < 8; ++bj)
      r += (vl[bj] > vl[bi]) || (vl[bj] == vl[bi] && bj < bi);
    if (r == rk) b = bi;
  }
  const int vlen = vl[b];
  const int q0 = i * 2;
  const int nc = (vlen + 63) >> 6;             // active 64-key chunks

  // ---- stage (Eq0, Eq1, wv) per u ----
  if (t < UU) {
    qpack[t] = make_float4(qp[(size_t)(b * QL + q0) * UU + t],
                           qp[(size_t)(b * QL + q0 + 1) * UU + t],
                           v_w[t], 0.f);
  }
  __syncthreads();

  // ---- score partials: wave w covers u in [32w, 32w+32), all keys ----
  {
    const float* __restrict__ kbase =
        kpT + ((size_t)(b * UU) + 32 * w) * KL + l;  // + u'*KL + 64c
    for (int c = 0; c < nc; ++c) {
      const int k64 = 64 * c;
      float a0 = 0.f, a1 = 0.f;
      float cb[8], nb[8];
#pragma unroll
      for (int j = 0; j < 8; ++j) cb[j] = kbase[(size_t)j * KL + k64];
#pragma unroll 1
      for (int ug = 0; ug < 32; ug += 8) {
        const int un = (ug + 8 < 32) ? ug + 8 : 0;   // clamped dummy on last
#pragma unroll
        for (int j = 0; j < 8; ++j) nb[j] = kbase[(size_t)(un + j) * KL + k64];
#pragma unroll
        for (int j = 0; j < 8; ++j) {
          const float4 qv = qpack[32 * w + ug + j];  // broadcast b128
          const float d0 = fmaf(qv.x, cb[j], 1.0f);  // 1 + e^{2(q0+k)}
          const float d1 = fmaf(qv.y, cb[j], 1.0f);  // 1 + e^{2(q1+k)}
          a0 = fmaf(qv.z, fast_rcp(d0), a0);
          a1 = fmaf(qv.z, fast_rcp(d1), a1);
        }
#pragma unroll
        for (int j = 0; j < 8; ++j) cb[j] = nb[j];
      }
      sp_part[w][c][l] = make_float2(a0, a1);  // lane-stride 8B: conflict-free
    }
  }
  __syncthreads();

  // ---- reduce partials: thread t owns key t (c = w, lane = l) ----
  float s0 = 0.f, s1 = 0.f;
#pragma unroll
  for (int ws = 0; ws < 8; ++ws) {
    const float2 p = sp_part[ws][w][l];        // keys in chunks >= nc are
    s0 += p.x; s1 += p.y;                      // garbage -> overwritten below
  }
  const int key = t;
  // score = -2*sum(v_w*sigmoid); constant sum(v_w) dropped (shift-invariant)
  s0 = (key < vlen) ? -(s0 + s0) : NEG_INF;    // ternary kills NaN/Inf
  s1 = (key < vlen) ? -(s1 + s1) : NEG_INF;

  // ---- softmax, in-register ----
  float mx0 = s0, mx1 = s1;
#pragma unroll
  for (int off = 32; off >= 1; off >>= 1) {
    mx0 = fmaxf(mx0, __shfl_xor(mx0, off, 64));
    mx1 = fmaxf(mx1, __shfl_xor(mx1, off, 64));
  }
  if (l == 0) redM[w] = make_float2(mx0, mx1);
  __syncthreads();
  float m0 = redM[0].x, m1 = redM[0].y;
#pragma unroll
  for (int j = 1; j < 8; ++j) {
    m0 = fmaxf(m0, redM[j].x);
    m1 = fmaxf(m1, redM[j].y);
  }

  const float e0 = __expf(s0 - m0);            // masked -> exactly 0
  const float e1 = __expf(s1 - m1);
  sps0[key] = e0;
  sps1[key] = e1;
  float ss0 = e0, ss1 = e1;
#pragma unroll
  for (int off = 32; off >= 1; off >>= 1) {
    ss0 += __shfl_xor(ss0, off, 64);
    ss1 += __shfl_xor(ss1, off, 64);
  }
  if (l == 0) redS[w] = make_float2(ss0, ss1);
  __syncthreads();
  float sum0 = redS[0].x, sum1 = redS[0].y;
#pragma unroll
  for (int j = 1; j < 8; ++j) {
    sum0 += redS[j].x;
    sum1 += redS[j].y;
  }
  const float inv0 = fast_rcp(sum0);           // sums >= 1
  const float inv1 = fast_rcp(sum1);

  // ---- PV: split-k over thread-halves; thread = (h, d) ----
  const int h = t >> 8, d = t & 255;
  const int kmax  = (vlen + 15) & ~15;         // sps beyond vlen is exactly 0
  const int khalf = ((kmax >> 1) + 15) & ~15;  // multiple of 16
  const int kst = h ? khalf : 0;
  const int ken = h ? kmax : khalf;

  float o0 = 0.f, o1 = 0.f;
  if (ken > kst) {
    const float* __restrict__ vb = value + (size_t)b * KL * DD + d;
    float vc[16], vn[16];
#pragma unroll
    for (int j = 0; j < 16; ++j) vc[j] = vb[(size_t)(kst + j) * DD];
#pragma unroll 1
    for (int k = kst; k < ken; k += 16) {
      const int kn = (k + 16 < ken) ? k + 16 : kst;
#pragma unroll
      for (int j = 0; j < 16; ++j) vn[j] = vb[(size_t)(kn + j) * DD];
      const float4* __restrict__ p4 = reinterpret_cast<const float4*>(sps0 + k);
      const float4* __restrict__ q4 = reinterpret_cast<const float4*>(sps1 + k);
      const float4 p0 = p4[0], p1 = p4[1], p2 = p4[2], p3 = p4[3];
      const float4 r0 = q4[0], r1 = q4[1], r2 = q4[2], r3 = q4[3];
      o0 = fmaf(p0.x, vc[0],  o0); o1 = fmaf(r0.x, vc[0],  o1);
      o0 = fmaf(p0.y, vc[1],  o0); o1 = fmaf(r0.y, vc[1],  o1);
      o0 = fmaf(p0.z, vc[2],  o0); o1 = fmaf(r0.z, vc[2],  o1);
      o0 = fmaf(p0.w, vc[3],  o0); o1 = fmaf(r0.w, vc[3],  o1);
      o0 = fmaf(p1.x, vc[4],  o0); o1 = fmaf(r1.x, vc[4],  o1);
      o0 = fmaf(p1.y, vc[5],  o0); o1 = fmaf(r1.y, vc[5],  o1);
      o0 = fmaf(p1.z, vc[6],  o0); o1 = fmaf(r1.z, vc[6],  o1);
      o0 = fmaf(p1.w, vc[7],  o0); o1 = fmaf(r1.w, vc[7],  o1);
      o0 = fmaf(p2.x, vc[8],  o0); o1 = fmaf(r2.x, vc[8],  o1);
      o0 = fmaf(p2.y, vc[9],  o0); o1 = fmaf(r2.y, vc[9],  o1);
      o0 = fmaf(p2.z, vc[10], o0); o1 = fmaf(r2.z, vc[10], o1);
      o0 = fmaf(p2.w, vc[11], o0); o1 = fmaf(r2.w, vc[11], o1);
      o0 = fmaf(p3.x, vc[12], o0); o1 = fmaf(r3.x, vc[12], o1);
      o0 = fmaf(p3.y, vc[13], o0); o1 = fmaf(r3.y, vc[13], o1);
      o0 = fmaf(p3.z, vc[14], o0); o1 = fmaf(r3.z, vc[14], o1);
      o0 = fmaf(p3.w, vc[15], o0); o1 = fmaf(r3.w, vc[15], o1);
#pragma unroll
      for (int j = 0; j < 16; ++j) vc[j] = vn[j];
    }
  }
  if (h) opart[d] = make_float2(o0, o1);
  __syncthreads();
  if (!h) {
    const float2 p = opart[d];
    out[(size_t)(b * QL + q0) * DD + d]     = (o0 + p.x) * inv0;
    out[(size_t)(b * QL + q0 + 1) * DD + d] = (o1 + p.y) * inv1;
  }
}

extern "C" void kernel_launch(void* const* d_in, const int* in_sizes, int n_in,
                              void* d_out, int out_size, void* d_ws, size_t ws_size,
                              hipStream_t stream) {
  const float* query     = (const float*)d_in[0];
  const float* key       = (const float*)d_in[1];
  const float* value     = (const float*)d_in[2];
  const int*   valid_len = (const int*)d_in[3];
  const float* Wq        = (const float*)d_in[4];
  const float* Wk        = (const float*)d_in[5];
  const float* v_w       = (const float*)d_in[6];
  float* out = (float*)d_out;

  float* qp  = (float*)d_ws;                        // B*QL*U floats (1 MB)
  float* kpT = qp + (size_t)Bsz * QL * UU;          // B*U*KL floats (4 MB)

  const int proj_blocks = (Bsz * QL + Bsz * KL) / PR;   // 1280
  proj_kernel<<<proj_blocks, 256, 0, stream>>>(query, key, Wq, Wk, valid_len,
                                               qp, kpT);

  const int fused_blocks = Bsz * QL / 2;            // 512: (b, q-pair) items
  fused_attn_kernel<<<fused_blocks, 512, 0, stream>>>(value, valid_len, v_w,
                                                      qp, kpT, out);
}